// Round 3
// baseline (1028.965 us; speedup 1.0000x reference)
//
#include <hip/hip_runtime.h>
#include <math.h>

#define NBINS 10
#define BLOCKS 768           // 3 blocks/CU (LDS-bound: 51.3 KB/block), 1 wave each
#define THREADS 64           // single-wave blocks: no __syncthreads needed anywhere
#define TILE_ROWS 64         // rows per wave-tile
#define ROW_F4 25            // C = 100 floats = 25 float4 per row
#define TILE_F4 (TILE_ROWS * ROW_F4)   // 1600 float4 = 25.6 KB per buffer
#define LPL 25               // global_load_lds per lane per tile (1600/64)

// ws layout: [0..9] counts, [10..19] sum_conf, [20..29] sum_acc, [30] done-counter

typedef const __attribute__((address_space(1))) void* gptr_t;
typedef __attribute__((address_space(3))) void* lptr_t;

__global__ void ece_zero_ws(float* ws) {
    int i = threadIdx.x;
    if (i < 3 * NBINS + 1) ws[i] = 0.0f;   // 0.0f bit-pattern also zeroes the u32 counter
}

// Double-buffered wave-private LDS staging with counted vmcnt (T3/T4 pattern):
//   stage(next) -> s_waitcnt vmcnt(25) [waits ONLY for current tile's 25 loads;
//   the 25 prefetch loads stay in flight across the compute phase] -> compute.
// Memory pipe never drains: ~77 KB in flight per CU vs ~9 KB Little's-law need.
// ece_final is fused in via a device-scope done-counter (saves one launch).
__global__ __launch_bounds__(THREADS) void ece_main(
        const float* __restrict__ logits,
        const int* __restrict__ labels,
        float* __restrict__ ws,
        float* __restrict__ out,
        int N) {
    __shared__ __align__(16) float bufA[TILE_ROWS * 100];  // 25.6 KB
    __shared__ __align__(16) float bufB[TILE_ROWS * 100];  // 25.6 KB
    __shared__ float sbin[3 * NBINS];

    const int lane = threadIdx.x;          // single wave: tid == lane
    if (lane < 3 * NBINS) sbin[lane] = 0.0f;
    // same wave writes then atomically updates sbin -> program order suffices.

    const long long nTiles = ((long long)N + TILE_ROWS - 1) / TILE_ROWS;
    const long long waveId = blockIdx.x;
    const long long nWaves = gridDim.x;

    const float4* const lg4 = (const float4*)logits;
    const long long lastF4 = (long long)N * ROW_F4 - 1;

    float* pa = bufA;
    float* pb = bufB;

    long long t = waveId;
    if (t < nTiles) {
        // prologue: stage first tile into pa
        {
            const long long base = t * (long long)TILE_F4;
            #pragma unroll
            for (int j = 0; j < LPL; ++j) {
                long long g = base + j * 64 + lane;
                if (g > lastF4) g = lastF4;          // tail clamp, dest stays linear
                __builtin_amdgcn_global_load_lds((gptr_t)(lg4 + g),
                                                 (lptr_t)(pa + j * 256), 16, 0, 0);
            }
        }
        for (; t < nTiles; t += nWaves) {
            // issue next tile's loads into pb (harmless clamped reads past the end)
            {
                const long long base = (t + nWaves) * (long long)TILE_F4;
                #pragma unroll
                for (int j = 0; j < LPL; ++j) {
                    long long g = base + j * 64 + lane;
                    if (g > lastF4) g = lastF4;
                    __builtin_amdgcn_global_load_lds((gptr_t)(lg4 + g),
                                                     (lptr_t)(pb + j * 256), 16, 0, 0);
                }
            }
            // wait for CURRENT tile only: 25 newest (prefetch) may remain in flight
            asm volatile("s_waitcnt vmcnt(25)" ::: "memory");

            const long long row = t * TILE_ROWS + lane;
            if (row < (long long)N) {
                const float4* const rp = (const float4*)(pa + lane * 100);
                float m = -INFINITY;
                int midx = 0;
                #pragma unroll
                for (int j = 0; j < ROW_F4; ++j) {
                    const float4 v = rp[j];
                    const int e = 4 * j;
                    if (v.x > m) { m = v.x; midx = e; }
                    if (v.y > m) { m = v.y; midx = e + 1; }
                    if (v.z > m) { m = v.z; midx = e + 2; }
                    if (v.w > m) { m = v.w; midx = e + 3; }
                }
                const float conf = expf(m);                  // log-prob -> prob (0,1]
                const int b = (int)ceilf(conf * 10.0f) - 1;  // bin (i/10,(i+1)/10]
                const float acc = (midx == labels[row]) ? 1.0f : 0.0f;
                if (b >= 0 && b < NBINS) {
                    atomicAdd(&sbin[b], 1.0f);
                    atomicAdd(&sbin[NBINS + b], conf);
                    atomicAdd(&sbin[2 * NBINS + b], acc);
                }
            }
            float* tmp = pa; pa = pb; pb = tmp;
        }
    }

    // flush block partials (single wave -> no barrier; data dep orders LDS read
    // before the dependent global atomic)
    if (lane < 3 * NBINS) {
        const float s = sbin[lane];
        if (s != 0.0f) atomicAdd(&ws[lane], s);
    }
    __threadfence();                       // drain + make partials device-visible
    if (lane == 0) {
        const unsigned int old = atomicAdd((unsigned int*)(ws + 30), 1u);
        if (old == gridDim.x - 1) {        // last block finishes: compute ECE
            __threadfence();
            float ece = 0.0f;
            for (int b = 0; b < NBINS; ++b) {
                // atomic read-back: coherent path, immune to stale L1 across XCDs
                const float cnt = atomicAdd(&ws[b], 0.0f);
                if (cnt > 0.0f) {
                    const float avg_conf = atomicAdd(&ws[NBINS + b], 0.0f) / cnt;
                    const float avg_acc  = atomicAdd(&ws[2 * NBINS + b], 0.0f) / cnt;
                    ece += fabsf(avg_conf - avg_acc) * (cnt / (float)N);
                }
            }
            out[0] = ece;
        }
    }
}

extern "C" void kernel_launch(void* const* d_in, const int* in_sizes, int n_in,
                              void* d_out, int out_size, void* d_ws, size_t ws_size,
                              hipStream_t stream) {
    const float* logits = (const float*)d_in[0];
    const int*   labels = (const int*)d_in[1];
    float* out = (float*)d_out;
    float* ws  = (float*)d_ws;

    const int N = in_sizes[1];          // 2,000,000 rows (C = 100)

    ece_zero_ws<<<1, 64, 0, stream>>>(ws);
    ece_main<<<BLOCKS, THREADS, 0, stream>>>(logits, labels, ws, out, N);
}